// Round 20
// baseline (183.605 us; speedup 1.0000x reference)
//
#include <hip/hip_runtime.h>

#define LSEQ 8192
#define NFFT 8192       // half-size complex FFT via even/odd real packing
#define NT2 512
#define CCH 2048
#define TWO_PI 6.283185307179586f
#define PI_F  3.14159265358979323846f
#define KSTRIDE 8208    // float2 stride per channel in K workspace (>=8193)

#define PRIO_HI() __builtin_amdgcn_s_setprio(1)
#define PRIO_LO() __builtin_amdgcn_s_setprio(0)

// LDS twiddle tables, TRANSPOSED layout [r][idx] (idx contiguous per lane ->
// conflict-free b128 reads).
#define TW8O   0              // 8  cols x 8 r
#define TW64O  64             // 64 cols x 8 r
#define TW16O  576            // 16 cols x 8 r
#define TW128O 704            // 128 cols x 8 r
#define TWTOT  1728           // 13.8 KB; ds(64K)+twt fits 2 blocks/CU

// Parity-preserving XOR swizzle. Hoist identity: SL2(i + 512*r) == SL2(i) + 512*r.
__device__ __forceinline__ int SL2(int i) { return i ^ (((i >> 4) & 15) << 1); }

__device__ __forceinline__ float2 cmul(float2 a, float2 b) {
    return b * a.x + make_float2(-b.y, b.x) * a.y;   // fma-contracted
}
__device__ __forceinline__ float2 conjf2(float2 a) { return make_float2(a.x, -a.y); }

template<int SGN>
__device__ __forceinline__ float2 muli(float2 t) {   // SGN * i * t
    return (SGN < 0) ? make_float2(t.y, -t.x) : make_float2(-t.y, t.x);
}

template<int SGN>
__device__ __forceinline__ void dft4(float2& a0, float2& a1, float2& a2, float2& a3) {
    float2 t0 = a0 + a2, t1 = a0 - a2, t2 = a1 + a3, t3 = a1 - a3;
    float2 u = muli<SGN>(t3);
    a0 = t0 + t2; a1 = t1 + u; a2 = t0 - t2; a3 = t1 - u;
}

template<int SGN>
__device__ __forceinline__ void dft8(float2& v0, float2& v1, float2& v2, float2& v3,
                                     float2& v4, float2& v5, float2& v6, float2& v7) {
    float2 e0 = v0, e1 = v2, e2 = v4, e3 = v6;
    float2 o0 = v1, o1 = v3, o2 = v5, o3 = v7;
    dft4<SGN>(e0, e1, e2, e3);
    dft4<SGN>(o0, o1, o2, o3);
    const float sg = (float)SGN;
    const float H = 0.7071067811865476f;
    float2 t1 = cmul(o1, make_float2( H, sg * H));
    float2 t2 = muli<SGN>(o2);
    float2 t3 = cmul(o3, make_float2(-H, sg * H));
    v0 = e0 + o0; v4 = e0 - o0;
    v1 = e1 + t1; v5 = e1 - t1;
    v2 = e2 + t2; v6 = e2 - t2;
    v3 = e3 + t3; v7 = e3 - t3;
}

// Pruned dft8: only outputs 0..3 (final inverse pass discards n >= 4096).
template<int SGN>
__device__ __forceinline__ void dft8_lo(float2& v0, float2& v1, float2& v2, float2& v3,
                                        float2 v4, float2 v5, float2 v6, float2 v7) {
    float2 e0 = v0, e1 = v2, e2 = v4, e3 = v6;
    float2 o0 = v1, o1 = v3, o2 = v5, o3 = v7;
    dft4<SGN>(e0, e1, e2, e3);
    dft4<SGN>(o0, o1, o2, o3);
    const float sg = (float)SGN;
    const float H = 0.7071067811865476f;
    float2 t1 = cmul(o1, make_float2( H, sg * H));
    float2 t2 = muli<SGN>(o2);
    float2 t3 = cmul(o3, make_float2(-H, sg * H));
    v0 = e0 + o0; v1 = e1 + t1; v2 = e2 + t2; v3 = e3 + t3;
}

__device__ __forceinline__ void rdr(const float2* p, float2& lo, float2& hi) {
    const float4 v = *reinterpret_cast<const float4*>(p);
    lo = make_float2(v.x, v.y);
    hi = make_float2(v.z, v.w);
}
__device__ __forceinline__ void wrr(float2* p, float2 lo, float2 hi) {
    *reinterpret_cast<float4*>(p) = make_float4(lo.x, lo.y, hi.x, hi.y);
}
__device__ __forceinline__ void wrp(float2* ds, int e, float2 lo, float2 hi) {
    wrr(&ds[SL2(e)], lo, hi);
}

// One-time table generation: 216 columns, one per low thread (transposed).
#define GEN_TWT {                                                             \
    if (tid < 216) {                                                          \
        int idx, ns, off; float sgn;                                          \
        if (tid < 8)       { idx = tid;      ns = 8;   off = TW8O;   sgn = -1.f; } \
        else if (tid < 72) { idx = tid - 8;  ns = 64;  off = TW64O;  sgn = -1.f; } \
        else if (tid < 88) { idx = tid - 72; ns = 16;  off = TW16O;  sgn =  1.f; } \
        else               { idx = tid - 88; ns = 128; off = TW128O; sgn =  1.f; } \
        float s_, c_;                                                         \
        __sincosf(sgn * TWO_PI / (float)(ns * 8) * (float)idx, &s_, &c_);     \
        const float2 w1 = make_float2(c_, s_);                                \
        float2 w = w1;                                                        \
        twt[off + ns + idx] = w;                                              \
        _Pragma("unroll")                                                     \
        for (int r = 2; r < 8; r++) { w = cmul(w, w1); twt[off + r * ns + idx] = w; } \
    }                                                                         \
}

// Radix-8 Stockham reads at stride 1024: swizzled base + offset immediates.
#define RD8X                                                                  \
    float2 a0,a1,a2,a3,a4,a5,a6,a7,b0,b1,b2,b3,b4,b5,b6,b7;                   \
    {   const float2* p_ = ds + SL2(B_);                                      \
        rdr(p_,        a0, b0);                                               \
        rdr(p_ + 1024, a1, b1);                                               \
        rdr(p_ + 2048, a2, b2);                                               \
        rdr(p_ + 3072, a3, b3);                                               \
        rdr(p_ + 4096, a4, b4);                                               \
        rdr(p_ + 5120, a5, b5);                                               \
        rdr(p_ + 6144, a6, b6);                                               \
        rdr(p_ + 7168, a7, b7);                                               \
    }

#define DFT8AB(SGN)                                                           \
    PRIO_HI();                                                                \
    dft8<(SGN)>(a0,a1,a2,a3,a4,a5,a6,a7);                                     \
    dft8<(SGN)>(b0,b1,b2,b3,b4,b5,b6,b7);                                     \
    PRIO_LO();

// Transposed table reads: one b128 at [r][idx] yields (wa^r, wb^r).
#define TWID_LDS(NSv, TOFF) {                                                 \
    const float2* ra_ = twt + (TOFF) + (B_ & ((NSv) - 1));                    \
    float2 ta_, tb_;                                                          \
    rdr(ra_ + 1 * (NSv), ta_, tb_); a1 = cmul(a1, ta_); b1 = cmul(b1, tb_);   \
    rdr(ra_ + 2 * (NSv), ta_, tb_); a2 = cmul(a2, ta_); b2 = cmul(b2, tb_);   \
    rdr(ra_ + 3 * (NSv), ta_, tb_); a3 = cmul(a3, ta_); b3 = cmul(b3, tb_);   \
    rdr(ra_ + 4 * (NSv), ta_, tb_); a4 = cmul(a4, ta_); b4 = cmul(b4, tb_);   \
    rdr(ra_ + 5 * (NSv), ta_, tb_); a5 = cmul(a5, ta_); b5 = cmul(b5, tb_);   \
    rdr(ra_ + 6 * (NSv), ta_, tb_); a6 = cmul(a6, ta_); b6 = cmul(b6, tb_);   \
    rdr(ra_ + 7 * (NSv), ta_, tb_); a7 = cmul(a7, ta_); b7 = cmul(b7, tb_);   \
}

// One sincos; squaring-tree powers; wb = wa * wD.  (final NS=1024 pass only)
#define TWID(SGN, NSv, WDC, WDS) {                                            \
    float s_, c_;                                                             \
    __sincosf((float)(SGN) * TWO_PI / (float)((NSv) * 8) *                    \
              (float)(B_ & ((NSv) - 1)), &s_, &c_);                           \
    const float2 w1a = make_float2(c_, s_);                                   \
    a1 = cmul(a1, w1a);                                                       \
    const float2 w2a = cmul(w1a, w1a);                                        \
    a2 = cmul(a2, w2a);                                                       \
    const float2 w3a = cmul(w2a, w1a);                                        \
    a3 = cmul(a3, w3a);                                                       \
    const float2 w4a = cmul(w2a, w2a);                                        \
    a4 = cmul(a4, w4a);                                                       \
    a5 = cmul(a5, cmul(w3a, w2a));                                            \
    a6 = cmul(a6, cmul(w3a, w3a));                                            \
    a7 = cmul(a7, cmul(w4a, w3a));                                            \
    const float2 w1b = cmul(w1a, make_float2((WDC), (float)(SGN) * (WDS)));   \
    b1 = cmul(b1, w1b);                                                       \
    const float2 w2b = cmul(w1b, w1b);                                        \
    b2 = cmul(b2, w2b);                                                       \
    const float2 w3b = cmul(w2b, w1b);                                        \
    b3 = cmul(b3, w3b);                                                       \
    const float2 w4b = cmul(w2b, w2b);                                        \
    b4 = cmul(b4, w4b);                                                       \
    b5 = cmul(b5, cmul(w3b, w2b));                                            \
    b6 = cmul(b6, cmul(w3b, w3b));                                            \
    b7 = cmul(b7, cmul(w4b, w3b));                                            \
}

#define WR8P(NSv) {                                                           \
    const int i_ = B_ & ((NSv) - 1);                                          \
    const int d_ = ((B_ - i_) << 3) + i_;                                     \
    wrp(ds, d_,             a0, b0);                                          \
    wrp(ds, d_ +     (NSv), a1, b1);                                          \
    wrp(ds, d_ + 2 * (NSv), a2, b2);                                          \
    wrp(ds, d_ + 3 * (NSv), a3, b3);                                          \
    wrp(ds, d_ + 4 * (NSv), a4, b4);                                          \
    wrp(ds, d_ + 5 * (NSv), a5, b5);                                          \
    wrp(ds, d_ + 6 * (NSv), a6, b6);                                          \
    wrp(ds, d_ + 7 * (NSv), a7, b7);                                          \
}

#define WR8SEQ {                                                              \
    const int d_ = B_ << 3;                                                   \
    wrp(ds, d_,      a0, a1);                                                 \
    wrp(ds, d_ +  2, a2, a3);                                                 \
    wrp(ds, d_ +  4, a4, a5);                                                 \
    wrp(ds, d_ +  6, a6, a7);                                                 \
    wrp(ds, d_ +  8, b0, b1);                                                 \
    wrp(ds, d_ + 10, b2, b3);                                                 \
    wrp(ds, d_ + 12, b4, b5);                                                 \
    wrp(ds, d_ + 14, b6, b7);                                                 \
}

// Mid pass with transposed LDS twiddle table.
#define P8MIDT(SGN, NSv, TOFF) {                                              \
    RD8X                                                                      \
    TWID_LDS(NSv, TOFF)                                                       \
    DFT8AB(SGN)                                                               \
    __syncthreads();                                                          \
    WR8P(NSv)                                                                 \
    __syncthreads();                                                          \
}

// wD = e^{2pi/(8*NS)} for the final pass.
#define WDF_C  0.9999997058628822f
#define WDF_S  0.0007669903187427045f

// Radix-16 DFT over named float2 scalars; X[k] ends in P{4*(k&3)+(k>>2)}.
#define DFT16M(SGN, P) {                                                            \
    PRIO_HI();                                                                      \
    dft4<(SGN)>(P##0, P##4, P##8,  P##12);                                          \
    dft4<(SGN)>(P##1, P##5, P##9,  P##13);                                          \
    dft4<(SGN)>(P##2, P##6, P##10, P##14);                                          \
    dft4<(SGN)>(P##3, P##7, P##11, P##15);                                          \
    const float sg_ = (float)(SGN);                                                 \
    const float2 tw1_ = make_float2( 0.9238795325112867f,  sg_ * 0.3826834323650898f); \
    const float2 tw2_ = make_float2( 0.7071067811865476f,  sg_ * 0.7071067811865476f); \
    const float2 tw3_ = make_float2( 0.3826834323650898f,  sg_ * 0.9238795325112867f); \
    const float2 tw6_ = make_float2(-0.7071067811865476f,  sg_ * 0.7071067811865476f); \
    const float2 tw9_ = make_float2(-0.9238795325112867f, -sg_ * 0.3826834323650898f); \
    P##5  = cmul(P##5,  tw1_);                                                      \
    P##6  = cmul(P##6,  tw2_);                                                      \
    P##7  = cmul(P##7,  tw3_);                                                      \
    P##9  = cmul(P##9,  tw2_);                                                      \
    P##10 = muli<(SGN)>(P##10);                                                     \
    P##11 = cmul(P##11, tw6_);                                                      \
    P##13 = cmul(P##13, tw3_);                                                      \
    P##14 = cmul(P##14, tw6_);                                                      \
    P##15 = cmul(P##15, tw9_);                                                      \
    dft4<(SGN)>(P##0,  P##1,  P##2,  P##3);                                         \
    dft4<(SGN)>(P##4,  P##5,  P##6,  P##7);                                         \
    dft4<(SGN)>(P##8,  P##9,  P##10, P##11);                                        \
    dft4<(SGN)>(P##12, P##13, P##14, P##15);                                        \
    PRIO_LO();                                                                      \
}

// Forward final radix-16 loads (hoisted base) + twiddle squaring tree.
#define R16_LOAD_TWIDDLE(SGN)                                                 \
    float2 m0,m1,m2,m3,m4,m5,m6,m7,m8,m9,m10,m11,m12,m13,m14,m15;             \
    {   const float2* p_ = ds + SL2(tid);                                     \
        m0  = p_[0];    m1  = p_[512];  m2  = p_[1024]; m3  = p_[1536];       \
        m4  = p_[2048]; m5  = p_[2560]; m6  = p_[3072]; m7  = p_[3584];       \
        m8  = p_[4096]; m9  = p_[4608]; m10 = p_[5120]; m11 = p_[5632];       \
        m12 = p_[6144]; m13 = p_[6656]; m14 = p_[7168]; m15 = p_[7680];       \
    }                                                                         \
    {   float s_, c_;                                                         \
        __sincosf((float)(SGN) * TWO_PI / 8192.0f * (float)tid, &s_, &c_);    \
        PRIO_HI();                                                            \
        const float2 w1 = make_float2(c_, s_);                                \
        m1 = cmul(m1, w1);                                                    \
        const float2 w2 = cmul(w1, w1);   m2  = cmul(m2,  w2);                \
        const float2 w3 = cmul(w2, w1);   m3  = cmul(m3,  w3);                \
        const float2 w4 = cmul(w2, w2);   m4  = cmul(m4,  w4);                \
        const float2 w5 = cmul(w3, w2);   m5  = cmul(m5,  w5);                \
        const float2 w6 = cmul(w3, w3);   m6  = cmul(m6,  w6);                \
        const float2 w7 = cmul(w4, w3);   m7  = cmul(m7,  w7);                \
        const float2 w8 = cmul(w4, w4);   m8  = cmul(m8,  w8);                \
        m9  = cmul(m9,  cmul(w5, w4));                                        \
        m10 = cmul(m10, cmul(w5, w5));                                        \
        m11 = cmul(m11, cmul(w6, w5));                                        \
        m12 = cmul(m12, cmul(w6, w6));                                        \
        m13 = cmul(m13, cmul(w7, w6));                                        \
        m14 = cmul(m14, cmul(w7, w7));                                        \
        m15 = cmul(m15, cmul(w8, w7));                                        \
        PRIO_LO();                                                            \
    }

// Store ONLY upper-half bins k=8..15 (own bins k=0..7 stay in registers).
#define R16_STORE_HI {                                                        \
    float2* p_ = ds + SL2(tid);                                               \
    p_[4096] = m2;  p_[4608] = m6;  p_[5120] = m10; p_[5632] = m14;           \
    p_[6144] = m3;  p_[6656] = m7;  p_[7168] = m11; p_[7680] = m15;           \
}

// Untangle rotation step: e^{i*pi/16}.
#define UE1 make_float2(0.9807852804032304f, 0.1950903220161283f)

// Pairwise untangle*K*tangle for pair (j, 8192-j), j = tid + 512*R.
#define PAIR(R, MW, KJ, KM, VOUT) {                                           \
    float2 Wm_ = ds[mb_ - 512 * (R)];                                         \
    float2 E_ = (MW + conjf2(Wm_)) * 0.5f;                                    \
    float2 D_ = (MW - conjf2(Wm_)) * 0.5f;                                    \
    float2 O_ = make_float2(D_.y, -D_.x);                                     \
    float2 Xj_ = E_ + cmul(O_, conjf2(cs));                                   \
    float2 Xm_ = conjf2(E_) - cmul(conjf2(O_), cs);                           \
    float2 Zj_ = cmul(Xj_, (KJ));                                             \
    float2 Zm_ = cmul(Xm_, (KM));                                             \
    float2 P_ = Zj_ + conjf2(Zm_);                                            \
    float2 Q_ = Zj_ - conjf2(Zm_);                                            \
    VOUT = P_ + cmul(Q_, make_float2(-cs.y, cs.x));                           \
    float2 P2_ = Zm_ + conjf2(Zj_);                                           \
    float2 Q2_ = Zm_ - conjf2(Zj_);                                           \
    ds[mb_ - 512 * (R)] = P2_ + cmul(Q2_, make_float2(-cs.y, -cs.x));         \
}

// ================= Kernel A: K half-spectrum (16384 rfft) -> workspace =================
__global__ __launch_bounds__(NT2)
void hyena_kfft8(const float* __restrict__ k, const float* __restrict__ bias,
                 float2* __restrict__ kw)
{
    __shared__ alignas(16) float2 ds[NFFT];           // 64 KiB
    __shared__ alignas(16) float2 twt[TWTOT];         // 13.8 KiB tables
    const int c = blockIdx.x, tid = threadIdx.x;
    const int B_ = tid << 1;
    const float* kp = k + (size_t)c * LSEQ;
    const float bsv = bias[c];

    GEN_TWT                                           // before pass0's barrier

    {   // pass0 (NS=1): w[e] = k[2e] + i*k[2e+1]; e >= 4096 is zero padding.
        float2 a0,a1,a2,a3,a4,a5,a6,a7,b0,b1,b2,b3,b4,b5,b6,b7;
        float4 v;
        v = *(const float4*)&kp[(B_ << 1)];
        a0 = make_float2(v.x, v.y); b0 = make_float2(v.z, v.w);
        if (tid == 0) a0.x += bsv;                    // bias = conv tap s=0
        v = *(const float4*)&kp[(B_ << 1) + 2048];
        a1 = make_float2(v.x, v.y); b1 = make_float2(v.z, v.w);
        v = *(const float4*)&kp[(B_ << 1) + 4096];
        a2 = make_float2(v.x, v.y); b2 = make_float2(v.z, v.w);
        v = *(const float4*)&kp[(B_ << 1) + 6144];
        a3 = make_float2(v.x, v.y); b3 = make_float2(v.z, v.w);
        a4 = a5 = a6 = a7 = b4 = b5 = b6 = b7 = make_float2(0.f, 0.f);
        DFT8AB(-1)
        WR8SEQ
        __syncthreads();                              // also fences twt writes
    }
    P8MIDT(-1, 8,  TW8O)
    P8MIDT(-1, 64, TW64O)

    // final radix-16 (NS=512); own bins in regs, upper half to LDS for mirrors.
    R16_LOAD_TWIDDLE(-1)
    DFT16M(-1, m)
    R16_STORE_HI
    __syncthreads();

    // Untangle to K[j] = rfft16384(k)[j] / 16384 (own W from registers).
    {
        const float sc = 1.0f / 16384.0f;
        float2* kc = kw + (size_t)c * KSTRIDE;
        const int mb_ = (tid == 0) ? 8192 : (7680 + SL2(512 - tid));
        float s0_, c0_;
        __sincosf(PI_F / 8192.0f * (float)tid, &s0_, &c0_);
        float2 cs = make_float2(c0_, s0_);
#define KPAIR(R, MW) {                                                        \
        float2 Wm_ = ds[mb_ - 512 * (R)];                                     \
        float2 E_ = (MW + conjf2(Wm_)) * 0.5f;                                \
        float2 D_ = (MW - conjf2(Wm_)) * 0.5f;                                \
        float2 O_ = make_float2(D_.y, -D_.x);                                 \
        kc[tid + 512 * (R)]        = (E_ + cmul(O_, conjf2(cs))) * sc;        \
        kc[8192 - tid - 512 * (R)] = (conjf2(E_) - cmul(conjf2(O_), cs)) * sc;\
    }
        if (tid == 0) {
            kc[0]    = make_float2((m0.x + m0.y) * sc, 0.f);
            kc[8192] = make_float2((m0.x - m0.y) * sc, 0.f);
            kc[4096] = make_float2(m2.x * sc, -m2.y * sc);   // conj(W[4096])*sc
        } else {
            KPAIR(0, m0)
        }
        cs = cmul(cs, UE1);
        KPAIR(1, m4)  cs = cmul(cs, UE1);
        KPAIR(2, m8)  cs = cmul(cs, UE1);
        KPAIR(3, m12) cs = cmul(cs, UE1);
        KPAIR(4, m1)  cs = cmul(cs, UE1);
        KPAIR(5, m5)  cs = cmul(cs, UE1);
        KPAIR(6, m9)  cs = cmul(cs, UE1);
        KPAIR(7, m13)
#undef KPAIR
    }
}

// ====== Kernel B: W=FFT(x even/odd) -> pair untangle*K*tangle (Vm-exchange)
//        -> fused inverse pass1 -> IFFT -> y ======
__global__ __launch_bounds__(NT2)
void hyena_xconv8(const float* __restrict__ x, const float2* __restrict__ kw,
                  float* __restrict__ y)
{
    __shared__ alignas(16) float2 ds[NFFT];           // 64 KiB
    __shared__ alignas(16) float2 twt[TWTOT];         // 13.8 KiB tables
    const int bid = blockIdx.x, tid = threadIdx.x;
    const int c = bid >> 1, b = bid & 1;              // adjacent blocks share K row
    const int B_ = tid << 1;
    const float* xp = x + ((size_t)(b * CCH + c)) * LSEQ;
    float*       yp = y + ((size_t)(b * CCH + c)) * LSEQ;

    GEN_TWT                                           // before pass0's barrier

    {   // forward pass0: w[e] = x[2e] + i*x[2e+1]; e >= 4096 zero.
        float2 a0,a1,a2,a3,a4,a5,a6,a7,b0,b1,b2,b3,b4,b5,b6,b7;
        float4 v;
        v = *(const float4*)&xp[(B_ << 1)];
        a0 = make_float2(v.x, v.y); b0 = make_float2(v.z, v.w);
        v = *(const float4*)&xp[(B_ << 1) + 2048];
        a1 = make_float2(v.x, v.y); b1 = make_float2(v.z, v.w);
        v = *(const float4*)&xp[(B_ << 1) + 4096];
        a2 = make_float2(v.x, v.y); b2 = make_float2(v.z, v.w);
        v = *(const float4*)&xp[(B_ << 1) + 6144];
        a3 = make_float2(v.x, v.y); b3 = make_float2(v.z, v.w);
        a4 = a5 = a6 = a7 = b4 = b5 = b6 = b7 = make_float2(0.f, 0.f);
        DFT8AB(-1)
        WR8SEQ
        __syncthreads();                              // also fences twt writes
    }
    P8MIDT(-1, 8,  TW8O)
    P8MIDT(-1, 64, TW64O)

    {   // K prefetch (issue-early): 17 L2-hot loads overlap the radix-16 work.
        const float2* kc = kw + (size_t)c * KSTRIDE;
        float2 kj0 = kc[tid],        km0 = kc[8192 - tid];
        float2 kj1 = kc[tid +  512], km1 = kc[7680 - tid];
        float2 kj2 = kc[tid + 1024], km2 = kc[7168 - tid];
        float2 kj3 = kc[tid + 1536], km3 = kc[6656 - tid];
        float2 kj4 = kc[tid + 2048], km4 = kc[6144 - tid];
        float2 kj5 = kc[tid + 2560], km5 = kc[5632 - tid];
        float2 kj6 = kc[tid + 3072], km6 = kc[5120 - tid];
        float2 kj7 = kc[tid + 3584], km7 = kc[4608 - tid];
        float2 k4n = make_float2(0.f, 0.f);
        if (tid == 0) k4n = kc[4096];
        float s0_, c0_;
        __sincosf(PI_F / 8192.0f * (float)tid, &s0_, &c0_);
        float2 cs = make_float2(c0_, s0_);

        // forward final r16 -> own bins in regs; upper half to LDS for mirrors.
        R16_LOAD_TWIDDLE(-1)
        DFT16M(-1, m)
        R16_STORE_HI
        __syncthreads();

        const int mb_ = (tid == 0) ? 8192 : (7680 + SL2(512 - tid));
        float2 v0,v1,v2,v3,v4,v5,v6,v7,v8,v9,v10,v11,v12,v13,v14,v15;

        if (tid == 0) {       // pair j=0: DC + Nyquist of the 16384-domain
            float X0 = m0.x + m0.y, XN = m0.x - m0.y;
            float2 Z0 = make_float2(kj0.x * X0, kj0.y * X0);   // kj0 = kc[0]
            float2 ZN = make_float2(km0.x * XN, km0.y * XN);   // km0 = kc[8192]
            v0 = make_float2(Z0.x + ZN.x - (Z0.y - ZN.y),
                             Z0.y + ZN.y + (Z0.x - ZN.x));
            float2 Z4 = cmul(conjf2(m2), k4n);                 // W[4096] = m2
            v8 = make_float2(2.f * Z4.x, -2.f * Z4.y);         // V[4096] self-pair
        } else {
            PAIR(0, m0, kj0, km0, v0)
        }
        cs = cmul(cs, UE1);
        PAIR(1, m4,  kj1, km1, v1)  cs = cmul(cs, UE1);
        PAIR(2, m8,  kj2, km2, v2)  cs = cmul(cs, UE1);
        PAIR(3, m12, kj3, km3, v3)  cs = cmul(cs, UE1);
        PAIR(4, m1,  kj4, km4, v4)  cs = cmul(cs, UE1);
        PAIR(5, m5,  kj5, km5, v5)  cs = cmul(cs, UE1);
        PAIR(6, m9,  kj6, km6, v6)  cs = cmul(cs, UE1);
        PAIR(7, m13, kj7, km7, v7)
        __syncthreads();                               // Vm halves visible

        {   // read exchanged Vm halves: own class slots k=8..15
            const float2* p_ = ds + SL2(tid);
            if (tid != 0) v8 = p_[4096];               // tid 0 keeps Nyquist
            v9  = p_[4608]; v10 = p_[5120]; v11 = p_[5632];
            v12 = p_[6144]; v13 = p_[6656]; v14 = p_[7168]; v15 = p_[7680];
        }
        DFT16M(1, v)                                   // inverse pass1, no twiddle
        __syncthreads();                               // all Vm reads complete
        const int d0_ = tid << 4;                      // outputs -> 16j+q (paired)
        wrp(ds, d0_,      v0,  v4);
        wrp(ds, d0_ +  2, v8,  v12);
        wrp(ds, d0_ +  4, v1,  v5);
        wrp(ds, d0_ +  6, v9,  v13);
        wrp(ds, d0_ +  8, v2,  v6);
        wrp(ds, d0_ + 10, v10, v14);
        wrp(ds, d0_ + 12, v3,  v7);
        wrp(ds, d0_ + 14, v11, v15);
        __syncthreads();
    }

    // inverse mid passes: [r8 NS=16], [r8 NS=128] (transposed LDS tables)
    P8MIDT(1, 16,  TW16O)
    P8MIDT(1, 128, TW128O)

    {   // inverse final: r8 NS=1024, class-local; only n < 4096 needed.
        RD8X
        TWID(1, 1024, WDF_C, WDF_S)
        PRIO_HI();
        dft8_lo<1>(a0, a1, a2, a3, a4, a5, a6, a7);
        dft8_lo<1>(b0, b1, b2, b3, b4, b5, b6, b7);
        PRIO_LO();
        *(float4*)&yp[(B_) << 1]        = make_float4(a0.x, a0.y, b0.x, b0.y);
        *(float4*)&yp[(B_ + 1024) << 1] = make_float4(a1.x, a1.y, b1.x, b1.y);
        *(float4*)&yp[(B_ + 2048) << 1] = make_float4(a2.x, a2.y, b2.x, b2.y);
        *(float4*)&yp[(B_ + 3072) << 1] = make_float4(a3.x, a3.y, b3.x, b3.y);
    }
}

extern "C" void kernel_launch(void* const* d_in, const int* in_sizes, int n_in,
                              void* d_out, int out_size, void* d_ws, size_t ws_size,
                              hipStream_t stream) {
    const float* x    = (const float*)d_in[0];
    const float* k    = (const float*)d_in[1];
    const float* bias = (const float*)d_in[2];
    float* y          = (float*)d_out;
    float2* kw        = (float2*)d_ws;   // 2048 * KSTRIDE float2 (~134 MB)

    hyena_kfft8 <<<dim3(CCH),     dim3(NT2), 0, stream>>>(k, bias, kw);
    hyena_xconv8<<<dim3(2 * CCH), dim3(NT2), 0, stream>>>(x, kw, y);
}

// Round 21
// 177.929 us; speedup vs baseline: 1.0319x; 1.0319x over previous
//
#include <hip/hip_runtime.h>

#define LSEQ 8192
#define NFFT 8192       // half-size complex FFT via even/odd real packing
#define NT2 512
#define CCH 2048
#define TWO_PI 6.283185307179586f
#define PI_F  3.14159265358979323846f
#define KSTRIDE 8208    // float2 stride per channel in K workspace (>=8193)

// LDS twiddle tables, TRANSPOSED layout [r][idx] (idx contiguous per lane ->
// conflict-free b128 reads; [idx][r] 64B-row layout bank-collapsed in R18).
#define TW8O   0              // 8  cols x 8 r
#define TW64O  64             // 64 cols x 8 r
#define TW16O  576            // 16 cols x 8 r
#define TW128O 704            // 128 cols x 8 r
#define TWTOT  1728           // 13.8 KB; ds(64K)+twt fits 2 blocks/CU

// Parity-preserving XOR swizzle. Hoist identity: SL2(i + 512*r) == SL2(i) + 512*r.
__device__ __forceinline__ int SL2(int i) { return i ^ (((i >> 4) & 15) << 1); }

__device__ __forceinline__ float2 cmul(float2 a, float2 b) {
    return b * a.x + make_float2(-b.y, b.x) * a.y;   // fma-contracted
}
__device__ __forceinline__ float2 conjf2(float2 a) { return make_float2(a.x, -a.y); }

template<int SGN>
__device__ __forceinline__ float2 muli(float2 t) {   // SGN * i * t
    return (SGN < 0) ? make_float2(t.y, -t.x) : make_float2(-t.y, t.x);
}

template<int SGN>
__device__ __forceinline__ void dft4(float2& a0, float2& a1, float2& a2, float2& a3) {
    float2 t0 = a0 + a2, t1 = a0 - a2, t2 = a1 + a3, t3 = a1 - a3;
    float2 u = muli<SGN>(t3);
    a0 = t0 + t2; a1 = t1 + u; a2 = t0 - t2; a3 = t1 - u;
}

template<int SGN>
__device__ __forceinline__ void dft8(float2& v0, float2& v1, float2& v2, float2& v3,
                                     float2& v4, float2& v5, float2& v6, float2& v7) {
    float2 e0 = v0, e1 = v2, e2 = v4, e3 = v6;
    float2 o0 = v1, o1 = v3, o2 = v5, o3 = v7;
    dft4<SGN>(e0, e1, e2, e3);
    dft4<SGN>(o0, o1, o2, o3);
    const float sg = (float)SGN;
    const float H = 0.7071067811865476f;
    float2 t1 = cmul(o1, make_float2( H, sg * H));
    float2 t2 = muli<SGN>(o2);
    float2 t3 = cmul(o3, make_float2(-H, sg * H));
    v0 = e0 + o0; v4 = e0 - o0;
    v1 = e1 + t1; v5 = e1 - t1;
    v2 = e2 + t2; v6 = e2 - t2;
    v3 = e3 + t3; v7 = e3 - t3;
}

// Pruned dft8: only outputs 0..3 (final inverse pass discards n >= 4096).
template<int SGN>
__device__ __forceinline__ void dft8_lo(float2& v0, float2& v1, float2& v2, float2& v3,
                                        float2 v4, float2 v5, float2 v6, float2 v7) {
    float2 e0 = v0, e1 = v2, e2 = v4, e3 = v6;
    float2 o0 = v1, o1 = v3, o2 = v5, o3 = v7;
    dft4<SGN>(e0, e1, e2, e3);
    dft4<SGN>(o0, o1, o2, o3);
    const float sg = (float)SGN;
    const float H = 0.7071067811865476f;
    float2 t1 = cmul(o1, make_float2( H, sg * H));
    float2 t2 = muli<SGN>(o2);
    float2 t3 = cmul(o3, make_float2(-H, sg * H));
    v0 = e0 + o0; v1 = e1 + t1; v2 = e2 + t2; v3 = e3 + t3;
}

__device__ __forceinline__ void rdr(const float2* p, float2& lo, float2& hi) {
    const float4 v = *reinterpret_cast<const float4*>(p);
    lo = make_float2(v.x, v.y);
    hi = make_float2(v.z, v.w);
}
__device__ __forceinline__ void wrr(float2* p, float2 lo, float2 hi) {
    *reinterpret_cast<float4*>(p) = make_float4(lo.x, lo.y, hi.x, hi.y);
}
__device__ __forceinline__ void wrp(float2* ds, int e, float2 lo, float2 hi) {
    wrr(&ds[SL2(e)], lo, hi);
}

// One-time table generation: 216 columns, one per low thread (transposed).
#define GEN_TWT {                                                             \
    if (tid < 216) {                                                          \
        int idx, ns, off; float sgn;                                          \
        if (tid < 8)       { idx = tid;      ns = 8;   off = TW8O;   sgn = -1.f; } \
        else if (tid < 72) { idx = tid - 8;  ns = 64;  off = TW64O;  sgn = -1.f; } \
        else if (tid < 88) { idx = tid - 72; ns = 16;  off = TW16O;  sgn =  1.f; } \
        else               { idx = tid - 88; ns = 128; off = TW128O; sgn =  1.f; } \
        float s_, c_;                                                         \
        __sincosf(sgn * TWO_PI / (float)(ns * 8) * (float)idx, &s_, &c_);     \
        const float2 w1 = make_float2(c_, s_);                                \
        float2 w = w1;                                                        \
        twt[off + ns + idx] = w;                                              \
        _Pragma("unroll")                                                     \
        for (int r = 2; r < 8; r++) { w = cmul(w, w1); twt[off + r * ns + idx] = w; } \
    }                                                                         \
}

// Radix-8 Stockham reads at stride 1024: swizzled base + offset immediates.
#define RD8X                                                                  \
    float2 a0,a1,a2,a3,a4,a5,a6,a7,b0,b1,b2,b3,b4,b5,b6,b7;                   \
    {   const float2* p_ = ds + SL2(B_);                                      \
        rdr(p_,        a0, b0);                                               \
        rdr(p_ + 1024, a1, b1);                                               \
        rdr(p_ + 2048, a2, b2);                                               \
        rdr(p_ + 3072, a3, b3);                                               \
        rdr(p_ + 4096, a4, b4);                                               \
        rdr(p_ + 5120, a5, b5);                                               \
        rdr(p_ + 6144, a6, b6);                                               \
        rdr(p_ + 7168, a7, b7);                                               \
    }

#define DFT8AB(SGN)                                                           \
    dft8<(SGN)>(a0,a1,a2,a3,a4,a5,a6,a7);                                     \
    dft8<(SGN)>(b0,b1,b2,b3,b4,b5,b6,b7);

// Transposed table reads: one b128 at [r][idx] yields (wa^r, wb^r).
#define TWID_LDS(NSv, TOFF) {                                                 \
    const float2* ra_ = twt + (TOFF) + (B_ & ((NSv) - 1));                    \
    float2 ta_, tb_;                                                          \
    rdr(ra_ + 1 * (NSv), ta_, tb_); a1 = cmul(a1, ta_); b1 = cmul(b1, tb_);   \
    rdr(ra_ + 2 * (NSv), ta_, tb_); a2 = cmul(a2, ta_); b2 = cmul(b2, tb_);   \
    rdr(ra_ + 3 * (NSv), ta_, tb_); a3 = cmul(a3, ta_); b3 = cmul(b3, tb_);   \
    rdr(ra_ + 4 * (NSv), ta_, tb_); a4 = cmul(a4, ta_); b4 = cmul(b4, tb_);   \
    rdr(ra_ + 5 * (NSv), ta_, tb_); a5 = cmul(a5, ta_); b5 = cmul(b5, tb_);   \
    rdr(ra_ + 6 * (NSv), ta_, tb_); a6 = cmul(a6, ta_); b6 = cmul(b6, tb_);   \
    rdr(ra_ + 7 * (NSv), ta_, tb_); a7 = cmul(a7, ta_); b7 = cmul(b7, tb_);   \
}

// One sincos; squaring-tree powers; wb = wa * wD.  (final NS=1024 pass only)
#define TWID(SGN, NSv, WDC, WDS) {                                            \
    float s_, c_;                                                             \
    __sincosf((float)(SGN) * TWO_PI / (float)((NSv) * 8) *                    \
              (float)(B_ & ((NSv) - 1)), &s_, &c_);                           \
    const float2 w1a = make_float2(c_, s_);                                   \
    a1 = cmul(a1, w1a);                                                       \
    const float2 w2a = cmul(w1a, w1a);                                        \
    a2 = cmul(a2, w2a);                                                       \
    const float2 w3a = cmul(w2a, w1a);                                        \
    a3 = cmul(a3, w3a);                                                       \
    const float2 w4a = cmul(w2a, w2a);                                        \
    a4 = cmul(a4, w4a);                                                       \
    a5 = cmul(a5, cmul(w3a, w2a));                                            \
    a6 = cmul(a6, cmul(w3a, w3a));                                            \
    a7 = cmul(a7, cmul(w4a, w3a));                                            \
    const float2 w1b = cmul(w1a, make_float2((WDC), (float)(SGN) * (WDS)));   \
    b1 = cmul(b1, w1b);                                                       \
    const float2 w2b = cmul(w1b, w1b);                                        \
    b2 = cmul(b2, w2b);                                                       \
    const float2 w3b = cmul(w2b, w1b);                                        \
    b3 = cmul(b3, w3b);                                                       \
    const float2 w4b = cmul(w2b, w2b);                                        \
    b4 = cmul(b4, w4b);                                                       \
    b5 = cmul(b5, cmul(w3b, w2b));                                            \
    b6 = cmul(b6, cmul(w3b, w3b));                                            \
    b7 = cmul(b7, cmul(w4b, w3b));                                            \
}

#define WR8P(NSv) {                                                           \
    const int i_ = B_ & ((NSv) - 1);                                          \
    const int d_ = ((B_ - i_) << 3) + i_;                                     \
    wrp(ds, d_,             a0, b0);                                          \
    wrp(ds, d_ +     (NSv), a1, b1);                                          \
    wrp(ds, d_ + 2 * (NSv), a2, b2);                                          \
    wrp(ds, d_ + 3 * (NSv), a3, b3);                                          \
    wrp(ds, d_ + 4 * (NSv), a4, b4);                                          \
    wrp(ds, d_ + 5 * (NSv), a5, b5);                                          \
    wrp(ds, d_ + 6 * (NSv), a6, b6);                                          \
    wrp(ds, d_ + 7 * (NSv), a7, b7);                                          \
}

#define WR8SEQ {                                                              \
    const int d_ = B_ << 3;                                                   \
    wrp(ds, d_,      a0, a1);                                                 \
    wrp(ds, d_ +  2, a2, a3);                                                 \
    wrp(ds, d_ +  4, a4, a5);                                                 \
    wrp(ds, d_ +  6, a6, a7);                                                 \
    wrp(ds, d_ +  8, b0, b1);                                                 \
    wrp(ds, d_ + 10, b2, b3);                                                 \
    wrp(ds, d_ + 12, b4, b5);                                                 \
    wrp(ds, d_ + 14, b6, b7);                                                 \
}

// Mid pass with transposed LDS twiddle table.
#define P8MIDT(SGN, NSv, TOFF) {                                              \
    RD8X                                                                      \
    TWID_LDS(NSv, TOFF)                                                       \
    DFT8AB(SGN)                                                               \
    __syncthreads();                                                          \
    WR8P(NSv)                                                                 \
    __syncthreads();                                                          \
}

// wD = e^{2pi/(8*NS)} for the final pass.
#define WDF_C  0.9999997058628822f
#define WDF_S  0.0007669903187427045f

// Radix-16 DFT over named float2 scalars; X[k] ends in P{4*(k&3)+(k>>2)}.
#define DFT16M(SGN, P) {                                                            \
    dft4<(SGN)>(P##0, P##4, P##8,  P##12);                                          \
    dft4<(SGN)>(P##1, P##5, P##9,  P##13);                                          \
    dft4<(SGN)>(P##2, P##6, P##10, P##14);                                          \
    dft4<(SGN)>(P##3, P##7, P##11, P##15);                                          \
    const float sg_ = (float)(SGN);                                                 \
    const float2 tw1_ = make_float2( 0.9238795325112867f,  sg_ * 0.3826834323650898f); \
    const float2 tw2_ = make_float2( 0.7071067811865476f,  sg_ * 0.7071067811865476f); \
    const float2 tw3_ = make_float2( 0.3826834323650898f,  sg_ * 0.9238795325112867f); \
    const float2 tw6_ = make_float2(-0.7071067811865476f,  sg_ * 0.7071067811865476f); \
    const float2 tw9_ = make_float2(-0.9238795325112867f, -sg_ * 0.3826834323650898f); \
    P##5  = cmul(P##5,  tw1_);                                                      \
    P##6  = cmul(P##6,  tw2_);                                                      \
    P##7  = cmul(P##7,  tw3_);                                                      \
    P##9  = cmul(P##9,  tw2_);                                                      \
    P##10 = muli<(SGN)>(P##10);                                                     \
    P##11 = cmul(P##11, tw6_);                                                      \
    P##13 = cmul(P##13, tw3_);                                                      \
    P##14 = cmul(P##14, tw6_);                                                      \
    P##15 = cmul(P##15, tw9_);                                                      \
    dft4<(SGN)>(P##0,  P##1,  P##2,  P##3);                                         \
    dft4<(SGN)>(P##4,  P##5,  P##6,  P##7);                                         \
    dft4<(SGN)>(P##8,  P##9,  P##10, P##11);                                        \
    dft4<(SGN)>(P##12, P##13, P##14, P##15);                                        \
}

// Forward final radix-16 loads (hoisted base) + twiddle squaring tree.
#define R16_LOAD_TWIDDLE(SGN)                                                 \
    float2 m0,m1,m2,m3,m4,m5,m6,m7,m8,m9,m10,m11,m12,m13,m14,m15;             \
    {   const float2* p_ = ds + SL2(tid);                                     \
        m0  = p_[0];    m1  = p_[512];  m2  = p_[1024]; m3  = p_[1536];       \
        m4  = p_[2048]; m5  = p_[2560]; m6  = p_[3072]; m7  = p_[3584];       \
        m8  = p_[4096]; m9  = p_[4608]; m10 = p_[5120]; m11 = p_[5632];       \
        m12 = p_[6144]; m13 = p_[6656]; m14 = p_[7168]; m15 = p_[7680];       \
    }                                                                         \
    {   float s_, c_;                                                         \
        __sincosf((float)(SGN) * TWO_PI / 8192.0f * (float)tid, &s_, &c_);    \
        const float2 w1 = make_float2(c_, s_);                                \
        m1 = cmul(m1, w1);                                                    \
        const float2 w2 = cmul(w1, w1);   m2  = cmul(m2,  w2);                \
        const float2 w3 = cmul(w2, w1);   m3  = cmul(m3,  w3);                \
        const float2 w4 = cmul(w2, w2);   m4  = cmul(m4,  w4);                \
        const float2 w5 = cmul(w3, w2);   m5  = cmul(m5,  w5);                \
        const float2 w6 = cmul(w3, w3);   m6  = cmul(m6,  w6);                \
        const float2 w7 = cmul(w4, w3);   m7  = cmul(m7,  w7);                \
        const float2 w8 = cmul(w4, w4);   m8  = cmul(m8,  w8);                \
        m9  = cmul(m9,  cmul(w5, w4));                                        \
        m10 = cmul(m10, cmul(w5, w5));                                        \
        m11 = cmul(m11, cmul(w6, w5));                                        \
        m12 = cmul(m12, cmul(w6, w6));                                        \
        m13 = cmul(m13, cmul(w7, w6));                                        \
        m14 = cmul(m14, cmul(w7, w7));                                        \
        m15 = cmul(m15, cmul(w8, w7));                                        \
    }

// Store ONLY upper-half bins k=8..15 (own bins k=0..7 stay in registers).
#define R16_STORE_HI {                                                        \
    float2* p_ = ds + SL2(tid);                                               \
    p_[4096] = m2;  p_[4608] = m6;  p_[5120] = m10; p_[5632] = m14;           \
    p_[6144] = m3;  p_[6656] = m7;  p_[7168] = m11; p_[7680] = m15;           \
}

// Untangle rotation step: e^{i*pi/16}.
#define UE1 make_float2(0.9807852804032304f, 0.1950903220161283f)

// Pairwise untangle*K*tangle for pair (j, 8192-j), j = tid + 512*R.
// K values preloaded into registers (KJ/KM) before the barrier (T14).
#define PAIR(R, MW, KJ, KM, VOUT) {                                           \
    float2 Wm_ = ds[mb_ - 512 * (R)];                                         \
    float2 E_ = (MW + conjf2(Wm_)) * 0.5f;                                    \
    float2 D_ = (MW - conjf2(Wm_)) * 0.5f;                                    \
    float2 O_ = make_float2(D_.y, -D_.x);                                     \
    float2 Xj_ = E_ + cmul(O_, conjf2(cs));                                   \
    float2 Xm_ = conjf2(E_) - cmul(conjf2(O_), cs);                           \
    float2 Zj_ = cmul(Xj_, (KJ));                                             \
    float2 Zm_ = cmul(Xm_, (KM));                                             \
    float2 P_ = Zj_ + conjf2(Zm_);                                            \
    float2 Q_ = Zj_ - conjf2(Zm_);                                            \
    VOUT = P_ + cmul(Q_, make_float2(-cs.y, cs.x));                           \
    float2 P2_ = Zm_ + conjf2(Zj_);                                           \
    float2 Q2_ = Zm_ - conjf2(Zj_);                                           \
    ds[mb_ - 512 * (R)] = P2_ + cmul(Q2_, make_float2(-cs.y, -cs.x));         \
}

// ================= Kernel A: K half-spectrum (16384 rfft) -> workspace =================
__global__ __launch_bounds__(NT2)
void hyena_kfft8(const float* __restrict__ k, const float* __restrict__ bias,
                 float2* __restrict__ kw)
{
    __shared__ alignas(16) float2 ds[NFFT];           // 64 KiB
    __shared__ alignas(16) float2 twt[TWTOT];         // 13.8 KiB tables
    const int c = blockIdx.x, tid = threadIdx.x;
    const int B_ = tid << 1;
    const float* kp = k + (size_t)c * LSEQ;
    const float bsv = bias[c];

    GEN_TWT                                           // before pass0's barrier

    {   // pass0 (NS=1): w[e] = k[2e] + i*k[2e+1]; e >= 4096 is zero padding.
        float2 a0,a1,a2,a3,a4,a5,a6,a7,b0,b1,b2,b3,b4,b5,b6,b7;
        float4 v;
        v = *(const float4*)&kp[(B_ << 1)];
        a0 = make_float2(v.x, v.y); b0 = make_float2(v.z, v.w);
        if (tid == 0) a0.x += bsv;                    // bias = conv tap s=0
        v = *(const float4*)&kp[(B_ << 1) + 2048];
        a1 = make_float2(v.x, v.y); b1 = make_float2(v.z, v.w);
        v = *(const float4*)&kp[(B_ << 1) + 4096];
        a2 = make_float2(v.x, v.y); b2 = make_float2(v.z, v.w);
        v = *(const float4*)&kp[(B_ << 1) + 6144];
        a3 = make_float2(v.x, v.y); b3 = make_float2(v.z, v.w);
        a4 = a5 = a6 = a7 = b4 = b5 = b6 = b7 = make_float2(0.f, 0.f);
        DFT8AB(-1)
        WR8SEQ
        __syncthreads();                              // also fences twt writes
    }
    P8MIDT(-1, 8,  TW8O)
    P8MIDT(-1, 64, TW64O)

    // final radix-16 (NS=512); own bins in regs, upper half to LDS for mirrors.
    R16_LOAD_TWIDDLE(-1)
    DFT16M(-1, m)
    R16_STORE_HI
    __syncthreads();

    // Untangle to K[j] = rfft16384(k)[j] / 16384 (own W from registers).
    {
        const float sc = 1.0f / 16384.0f;
        float2* kc = kw + (size_t)c * KSTRIDE;
        const int mb_ = (tid == 0) ? 8192 : (7680 + SL2(512 - tid));
        float s0_, c0_;
        __sincosf(PI_F / 8192.0f * (float)tid, &s0_, &c0_);
        float2 cs = make_float2(c0_, s0_);
#define KPAIR(R, MW) {                                                        \
        float2 Wm_ = ds[mb_ - 512 * (R)];                                     \
        float2 E_ = (MW + conjf2(Wm_)) * 0.5f;                                \
        float2 D_ = (MW - conjf2(Wm_)) * 0.5f;                                \
        float2 O_ = make_float2(D_.y, -D_.x);                                 \
        kc[tid + 512 * (R)]        = (E_ + cmul(O_, conjf2(cs))) * sc;        \
        kc[8192 - tid - 512 * (R)] = (conjf2(E_) - cmul(conjf2(O_), cs)) * sc;\
    }
        if (tid == 0) {
            kc[0]    = make_float2((m0.x + m0.y) * sc, 0.f);
            kc[8192] = make_float2((m0.x - m0.y) * sc, 0.f);
            kc[4096] = make_float2(m2.x * sc, -m2.y * sc);   // conj(W[4096])*sc
        } else {
            KPAIR(0, m0)
        }
        cs = cmul(cs, UE1);
        KPAIR(1, m4)  cs = cmul(cs, UE1);
        KPAIR(2, m8)  cs = cmul(cs, UE1);
        KPAIR(3, m12) cs = cmul(cs, UE1);
        KPAIR(4, m1)  cs = cmul(cs, UE1);
        KPAIR(5, m5)  cs = cmul(cs, UE1);
        KPAIR(6, m9)  cs = cmul(cs, UE1);
        KPAIR(7, m13)
#undef KPAIR
    }
}

// ====== Kernel B: W=FFT(x even/odd) -> pair untangle*K*tangle (Vm-exchange)
//        -> fused inverse pass1 -> IFFT -> y ======
__global__ __launch_bounds__(NT2)
void hyena_xconv8(const float* __restrict__ x, const float2* __restrict__ kw,
                  float* __restrict__ y)
{
    __shared__ alignas(16) float2 ds[NFFT];           // 64 KiB
    __shared__ alignas(16) float2 twt[TWTOT];         // 13.8 KiB tables
    const int bid = blockIdx.x, tid = threadIdx.x;
    const int c = bid >> 1, b = bid & 1;              // adjacent blocks share K row
    const int B_ = tid << 1;
    const float* xp = x + ((size_t)(b * CCH + c)) * LSEQ;
    float*       yp = y + ((size_t)(b * CCH + c)) * LSEQ;

    GEN_TWT                                           // before pass0's barrier

    {   // forward pass0: w[e] = x[2e] + i*x[2e+1]; e >= 4096 zero.
        float2 a0,a1,a2,a3,a4,a5,a6,a7,b0,b1,b2,b3,b4,b5,b6,b7;
        float4 v;
        v = *(const float4*)&xp[(B_ << 1)];
        a0 = make_float2(v.x, v.y); b0 = make_float2(v.z, v.w);
        v = *(const float4*)&xp[(B_ << 1) + 2048];
        a1 = make_float2(v.x, v.y); b1 = make_float2(v.z, v.w);
        v = *(const float4*)&xp[(B_ << 1) + 4096];
        a2 = make_float2(v.x, v.y); b2 = make_float2(v.z, v.w);
        v = *(const float4*)&xp[(B_ << 1) + 6144];
        a3 = make_float2(v.x, v.y); b3 = make_float2(v.z, v.w);
        a4 = a5 = a6 = a7 = b4 = b5 = b6 = b7 = make_float2(0.f, 0.f);
        DFT8AB(-1)
        WR8SEQ
        __syncthreads();                              // also fences twt writes
    }
    P8MIDT(-1, 8,  TW8O)
    P8MIDT(-1, 64, TW64O)

    {   // K prefetch (issue-early): 17 L2-hot loads overlap the radix-16 work.
        const float2* kc = kw + (size_t)c * KSTRIDE;
        float2 kj0 = kc[tid],        km0 = kc[8192 - tid];
        float2 kj1 = kc[tid +  512], km1 = kc[7680 - tid];
        float2 kj2 = kc[tid + 1024], km2 = kc[7168 - tid];
        float2 kj3 = kc[tid + 1536], km3 = kc[6656 - tid];
        float2 kj4 = kc[tid + 2048], km4 = kc[6144 - tid];
        float2 kj5 = kc[tid + 2560], km5 = kc[5632 - tid];
        float2 kj6 = kc[tid + 3072], km6 = kc[5120 - tid];
        float2 kj7 = kc[tid + 3584], km7 = kc[4608 - tid];
        float2 k4n = make_float2(0.f, 0.f);
        if (tid == 0) k4n = kc[4096];
        float s0_, c0_;
        __sincosf(PI_F / 8192.0f * (float)tid, &s0_, &c0_);
        float2 cs = make_float2(c0_, s0_);

        // forward final r16 -> own bins in regs; upper half to LDS for mirrors.
        R16_LOAD_TWIDDLE(-1)
        DFT16M(-1, m)
        R16_STORE_HI
        __syncthreads();

        const int mb_ = (tid == 0) ? 8192 : (7680 + SL2(512 - tid));
        float2 v0,v1,v2,v3,v4,v5,v6,v7,v8,v9,v10,v11,v12,v13,v14,v15;

        if (tid == 0) {       // pair j=0: DC + Nyquist of the 16384-domain
            float X0 = m0.x + m0.y, XN = m0.x - m0.y;
            float2 Z0 = make_float2(kj0.x * X0, kj0.y * X0);   // kj0 = kc[0]
            float2 ZN = make_float2(km0.x * XN, km0.y * XN);   // km0 = kc[8192]
            v0 = make_float2(Z0.x + ZN.x - (Z0.y - ZN.y),
                             Z0.y + ZN.y + (Z0.x - ZN.x));
            float2 Z4 = cmul(conjf2(m2), k4n);                 // W[4096] = m2
            v8 = make_float2(2.f * Z4.x, -2.f * Z4.y);         // V[4096] self-pair
        } else {
            PAIR(0, m0, kj0, km0, v0)
        }
        cs = cmul(cs, UE1);
        PAIR(1, m4,  kj1, km1, v1)  cs = cmul(cs, UE1);
        PAIR(2, m8,  kj2, km2, v2)  cs = cmul(cs, UE1);
        PAIR(3, m12, kj3, km3, v3)  cs = cmul(cs, UE1);
        PAIR(4, m1,  kj4, km4, v4)  cs = cmul(cs, UE1);
        PAIR(5, m5,  kj5, km5, v5)  cs = cmul(cs, UE1);
        PAIR(6, m9,  kj6, km6, v6)  cs = cmul(cs, UE1);
        PAIR(7, m13, kj7, km7, v7)
        __syncthreads();                               // Vm halves visible

        {   // read exchanged Vm halves: own class slots k=8..15
            const float2* p_ = ds + SL2(tid);
            if (tid != 0) v8 = p_[4096];               // tid 0 keeps Nyquist
            v9  = p_[4608]; v10 = p_[5120]; v11 = p_[5632];
            v12 = p_[6144]; v13 = p_[6656]; v14 = p_[7168]; v15 = p_[7680];
        }
        DFT16M(1, v)                                   // inverse pass1, no twiddle
        __syncthreads();                               // all Vm reads complete
        const int d0_ = tid << 4;                      // outputs -> 16j+q (paired)
        wrp(ds, d0_,      v0,  v4);
        wrp(ds, d0_ +  2, v8,  v12);
        wrp(ds, d0_ +  4, v1,  v5);
        wrp(ds, d0_ +  6, v9,  v13);
        wrp(ds, d0_ +  8, v2,  v6);
        wrp(ds, d0_ + 10, v10, v14);
        wrp(ds, d0_ + 12, v3,  v7);
        wrp(ds, d0_ + 14, v11, v15);
        __syncthreads();
    }

    // inverse mid passes: [r8 NS=16], [r8 NS=128] (transposed LDS tables)
    P8MIDT(1, 16,  TW16O)
    P8MIDT(1, 128, TW128O)

    {   // inverse final: r8 NS=1024, class-local; only n < 4096 needed.
        RD8X
        TWID(1, 1024, WDF_C, WDF_S)
        dft8_lo<1>(a0, a1, a2, a3, a4, a5, a6, a7);
        dft8_lo<1>(b0, b1, b2, b3, b4, b5, b6, b7);
        *(float4*)&yp[(B_) << 1]        = make_float4(a0.x, a0.y, b0.x, b0.y);
        *(float4*)&yp[(B_ + 1024) << 1] = make_float4(a1.x, a1.y, b1.x, b1.y);
        *(float4*)&yp[(B_ + 2048) << 1] = make_float4(a2.x, a2.y, b2.x, b2.y);
        *(float4*)&yp[(B_ + 3072) << 1] = make_float4(a3.x, a3.y, b3.x, b3.y);
    }
}

extern "C" void kernel_launch(void* const* d_in, const int* in_sizes, int n_in,
                              void* d_out, int out_size, void* d_ws, size_t ws_size,
                              hipStream_t stream) {
    const float* x    = (const float*)d_in[0];
    const float* k    = (const float*)d_in[1];
    const float* bias = (const float*)d_in[2];
    float* y          = (float*)d_out;
    float2* kw        = (float2*)d_ws;   // 2048 * KSTRIDE float2 (~134 MB)

    hyena_kfft8 <<<dim3(CCH),     dim3(NT2), 0, stream>>>(k, bias, kw);
    hyena_xconv8<<<dim3(2 * CCH), dim3(NT2), 0, stream>>>(x, kw, y);
}